// Round 10
// baseline (250.357 us; speedup 1.0000x reference)
//
#include <hip/hip_runtime.h>
#include <stdint.h>

#define HIDDEN 1024
#define BATCH  4
#define SEQ    2048
#define TOKENS (BATCH * SEQ)      // 8192
#define QKVD   (3 * HIDDEN)       // 3072

typedef unsigned short u16;
typedef __attribute__((ext_vector_type(8))) short   short8;   // 8 bf16 = 4 VGPRs
typedef __attribute__((ext_vector_type(8))) unsigned short ushort8;
typedef __attribute__((ext_vector_type(4))) float   floatx4;

// deterministic round-to-nearest-even f32 -> bf16 (no NaN inputs here)
__device__ __forceinline__ u16 f32_bf16_rne(float f) {
    unsigned int u = __float_as_uint(f);
    u += 0x7FFFu + ((u >> 16) & 1u);
    return (u16)(u >> 16);
}
__device__ __forceinline__ float bf16_f32(u16 u) {
    return __uint_as_float(((unsigned int)u) << 16);
}

// async global->LDS, 16B per lane. LDS dest is wave-uniform base + lane*16.
__device__ __forceinline__ void gl16(const u16* g, u16* l) {
    __builtin_amdgcn_global_load_lds(
        (const __attribute__((address_space(1))) void*)g,
        (__attribute__((address_space(3))) void*)l, 16, 0, 0);
}

// T1: XCD-chunked bijective blockIdx swizzle (requires nwg % 8 == 0; all
// our GEMM grids are 768/256/256).  Default dispatch round-robins flat ids
// across the 8 XCDs; remapping nid = (F%8)*chunk + F/8 gives each XCD a
// CONTIGUOUS row-band of the grid -> its 32 concurrent blocks share A/B
// panels in its private 4MB L2 (QKV: 21 A-panels + 12 B -> 8 rows + 12 B).
// Mechanism: the 4-phase pipeline covers ~240-480 cyc of staging latency;
// L2 hits (~200cy) are covered, L3/HBM (~600-900cy) stall the barrier.
__device__ __forceinline__ void xcd_swizzle(int& bx, int& by, int& bz) {
    const int gx = gridDim.x, gy = gridDim.y;
    const int n  = gx * gy * gridDim.z;
    const int F  = (blockIdx.z * gy + blockIdx.y) * gx + blockIdx.x;
    const int nid = (F & 7) * (n >> 3) + (F >> 3);
    bx = nid % gx;
    by = (nid / gx) % gy;
    bz = nid / (gx * gy);
}

// ---- sync macros (verbatim from measured-best rounds)
// QKV 4-phase (R1): keep newest 3 staging loads in flight across barrier.
#define SYNC3() do { __builtin_amdgcn_sched_barrier(0); \
    asm volatile("s_waitcnt vmcnt(3)\n\ts_barrier" ::: "memory"); } while (0)
// R3 8-phase (scores/PV): raw barrier / lgkm drain / counted vmcnt(4)
#define PBAR() do { __builtin_amdgcn_sched_barrier(0); \
    asm volatile("s_barrier" ::: "memory"); } while (0)
#define LG0() asm volatile("s_waitcnt lgkmcnt(0)" ::: "memory")
#define VM4() do { __builtin_amdgcn_sched_barrier(0); \
    asm volatile("s_waitcnt vmcnt(4)" ::: "memory"); } while (0)

// ---------------------------------------------------------------- convert
__global__ __launch_bounds__(256) void cvt2_bf16_kernel(
        const float* __restrict__ sa, const float* __restrict__ sb,
        u16* __restrict__ da, u16* __restrict__ db, int n4a, int n4tot) {
    int i = blockIdx.x * 256 + threadIdx.x;
    if (i >= n4tot) return;
    float4 v;
    if (i < n4a) v = ((const float4*)sa)[i];
    else         v = ((const float4*)sb)[i - n4a];
    ushort4 o;
    o.x = f32_bf16_rne(v.x); o.y = f32_bf16_rne(v.y);
    o.z = f32_bf16_rne(v.z); o.w = f32_bf16_rne(v.w);
    if (i < n4a) ((ushort4*)da)[i] = o;
    else         ((ushort4*)db)[i - n4a] = o;
}

// ---------------------------------------------------------------- QKV GEMM
// qkv = Xb @ Wb^T + bias.  Round-1 4-phase kernel (best QKV structure; all
// six measured within cross-round noise ~67-70us) + round-10 XCD swizzle.
// BM=128, BN=256, BK=64, 512 threads = 8 waves (2M x 4N), per-wave 64x64.
// Slab + XOR swizzle + vmcnt(3) pipeline verbatim (0 conflicts all session).
__global__ __launch_bounds__(512, 2) void gemm_qkv(
        const u16* __restrict__ A, const u16* __restrict__ B,
        u16* __restrict__ C, const float* __restrict__ bias) {
    __shared__ __align__(16) u16 lds[2][2][(128 + 256) * 32];   // 96 KB

    const int t    = threadIdx.x;
    const int lane = t & 63;
    const int wid  = t >> 6;
    const int wr   = wid >> 2;           // 0..1
    const int wc   = wid & 3;            // 0..3
    int sbx, sby, sbz;                   // grid (12, 64, 1): nwg=768, chunk=96
    xcd_swizzle(sbx, sby, sbz);
    const int bm   = sby * 128;
    const int bn   = sbx * 256;

    // staging source: thread t -> row t>>2, phys slot t&3,
    // global slot = (t&3) ^ ((row>>1)&3)
    const int rA  = t >> 2;
    const int sl  = (t & 3) ^ ((rA >> 1) & 3);
    const u16* gA  = A + (size_t)(bm + rA) * 1024 + sl * 8;
    const u16* gB0 = B + (size_t)(bn + rA) * 1024 + sl * 8;
    const u16* gB1 = gB0 + (size_t)128 * 1024;

    // fragment read geometry (verified 16x16x32 mappings)
    const int fr = lane & 15;
    const int kc = lane >> 4;
    const int fo = ((kc ^ ((fr >> 1) & 3)) << 4);
    const int aoffB = (wr * 64 + fr) * 64 + fo;
    const int boffB = (wc * 64 + fr) * 64 + fo;

    floatx4 acc[4][4];
#pragma unroll
    for (int i = 0; i < 4; i++)
#pragma unroll
        for (int j = 0; j < 4; j++) acc[i][j] = (floatx4){0.f, 0.f, 0.f, 0.f};

    short8 bfr0, bfr1, bfr2, bfr3, va0, va1;

#define LDB4(BASE) \
    bfr0 = *(const short8*)((BASE) + boffB);        \
    bfr1 = *(const short8*)((BASE) + boffB + 1024); \
    bfr2 = *(const short8*)((BASE) + boffB + 2048); \
    bfr3 = *(const short8*)((BASE) + boffB + 3072);

#define MFMA2(MI, A0, A1) \
    __builtin_amdgcn_s_setprio(1); \
    acc[MI][0]     = __builtin_amdgcn_mfma_f32_16x16x32_bf16(A0, bfr0, acc[MI][0], 0, 0, 0); \
    acc[MI][1]     = __builtin_amdgcn_mfma_f32_16x16x32_bf16(A0, bfr1, acc[MI][1], 0, 0, 0); \
    acc[MI][2]     = __builtin_amdgcn_mfma_f32_16x16x32_bf16(A0, bfr2, acc[MI][2], 0, 0, 0); \
    acc[MI][3]     = __builtin_amdgcn_mfma_f32_16x16x32_bf16(A0, bfr3, acc[MI][3], 0, 0, 0); \
    acc[(MI)+1][0] = __builtin_amdgcn_mfma_f32_16x16x32_bf16(A1, bfr0, acc[(MI)+1][0], 0, 0, 0); \
    acc[(MI)+1][1] = __builtin_amdgcn_mfma_f32_16x16x32_bf16(A1, bfr1, acc[(MI)+1][1], 0, 0, 0); \
    acc[(MI)+1][2] = __builtin_amdgcn_mfma_f32_16x16x32_bf16(A1, bfr2, acc[(MI)+1][2], 0, 0, 0); \
    acc[(MI)+1][3] = __builtin_amdgcn_mfma_f32_16x16x32_bf16(A1, bfr3, acc[(MI)+1][3], 0, 0, 0); \
    __builtin_amdgcn_s_setprio(0);

#define ITER(BUF, SBUF, SCOL) { \
    const char* As0_ = (const char*)&lds[BUF][0][0]; \
    const char* Bs0_ = As0_ + 8192; \
    const char* As1_ = (const char*)&lds[BUF][1][0]; \
    const char* Bs1_ = As1_ + 8192; \
    gl16(gA + (SCOL),       (u16*)((char*)&lds[SBUF][0][0]    + wid * 1024)); \
    LDB4(Bs0_); \
    va0 = *(const short8*)(As0_ + aoffB); \
    va1 = *(const short8*)(As0_ + aoffB + 1024); \
    MFMA2(0, va0, va1); \
    gl16(gB0 + (SCOL),      (u16*)((char*)&lds[SBUF][0][4096] + wid * 1024)); \
    gl16(gB1 + (SCOL),      (u16*)((char*)&lds[SBUF][0][8192] + wid * 1024)); \
    va0 = *(const short8*)(As0_ + aoffB + 2048); \
    va1 = *(const short8*)(As0_ + aoffB + 3072); \
    MFMA2(2, va0, va1); \
    SYNC3(); \
    gl16(gA + (SCOL) + 32,  (u16*)((char*)&lds[SBUF][1][0]    + wid * 1024)); \
    LDB4(Bs1_); \
    va0 = *(const short8*)(As1_ + aoffB); \
    va1 = *(const short8*)(As1_ + aoffB + 1024); \
    MFMA2(0, va0, va1); \
    gl16(gB0 + (SCOL) + 32, (u16*)((char*)&lds[SBUF][1][4096] + wid * 1024)); \
    gl16(gB1 + (SCOL) + 32, (u16*)((char*)&lds[SBUF][1][8192] + wid * 1024)); \
    va0 = *(const short8*)(As1_ + aoffB + 2048); \
    va1 = *(const short8*)(As1_ + aoffB + 3072); \
    MFMA2(2, va0, va1); \
    SYNC3(); }

    // prologue: tile 0 -> buf0 (ks0 set, ks1 set); vmcnt(3) drains the ks0
    // set, leaves the ks1 set in flight (= steady state).
    gl16(gA,       (u16*)((char*)&lds[0][0][0]    + wid * 1024));
    gl16(gB0,      (u16*)((char*)&lds[0][0][4096] + wid * 1024));
    gl16(gB1,      (u16*)((char*)&lds[0][0][8192] + wid * 1024));
    gl16(gA + 32,  (u16*)((char*)&lds[0][1][0]    + wid * 1024));
    gl16(gB0 + 32, (u16*)((char*)&lds[0][1][4096] + wid * 1024));
    gl16(gB1 + 32, (u16*)((char*)&lds[0][1][8192] + wid * 1024));
    SYNC3();

    const int nk = 1024 >> 6;            // 16 K-tiles
    for (int kt = 0; kt < nk; kt += 2) {
        const int c1 = (kt + 1) << 6;
        const int c2 = (kt + 2 < nk ? (kt + 2) : (nk - 1)) << 6;
        ITER(0, 1, c1)
        ITER(1, 0, c2)
    }
    asm volatile("s_waitcnt vmcnt(0)" ::: "memory");

#undef ITER
#undef MFMA2
#undef LDB4

    // epilogue: C/D 16x16 mapping col=lane&15, row=(lane>>4)*4+reg
    const int crow0 = bm + wr * 64 + kc * 4;
    const int ccol0 = bn + wc * 64 + fr;
    float bv[4];
#pragma unroll
    for (int ni = 0; ni < 4; ni++) bv[ni] = bias[ccol0 + ni * 16];
#pragma unroll
    for (int mi = 0; mi < 4; mi++)
#pragma unroll
        for (int ni = 0; ni < 4; ni++)
#pragma unroll
            for (int r = 0; r < 4; r++)
                C[(size_t)(crow0 + mi * 16 + r) * QKVD + (ccol0 + ni * 16)] =
                    f32_bf16_rne(acc[mi][ni][r] + bv[ni]);
}

// ---------------------------------------------------------------- GEMM (NT)
// Round-3 8-phase template (measured best for scores+PV) + XCD swizzle.
// C[M,N] = A[M,K]*B[N,K]^T.  BM=2*WM, BN=256, BK=64, 512 threads, 8 waves.
// EPI: 1 = bf16 store * scale (R9: halves scores write + softmax read);
//      2 = f32 store.
template <int EPI, int WM>
__global__ __launch_bounds__(512, 2) void gemm_bt(
        const u16* __restrict__ A, const u16* __restrict__ B,
        void* __restrict__ Cv, const float* __restrict__ bias,
        int K, int lda, int ldb, int ldc,
        size_t sA, size_t sB, size_t sC, float scale) {
    constexpr int BM    = 2 * WM;
    constexpr int MIH   = WM / 32;
    constexpr int ASLAB = BM * 64;
    constexpr int BSLAB = 256 * 64;
    constexpr int BUFB  = 2 * ASLAB + 2 * BSLAB;
    __shared__ __align__(16) char lds[2][BUFB];

    const int t    = threadIdx.x;
    const int lane = t & 63;
    const int wid  = t >> 6;
    const int wr   = wid >> 2;
    const int wc   = wid & 3;
    int sbx, sby, sbz;                   // nwg = 256 for both uses, chunk=32
    xcd_swizzle(sbx, sby, sbz);
    const int bm   = sby * BM;
    const int bn   = sbx * 256;

    const u16* Ab = A + (size_t)sbz * sA;
    const u16* Bb = B + (size_t)sbz * sB;

    const int r0 = t >> 2;
    const int sl = (t & 3) ^ ((r0 >> 1) & 3);
    const u16* gA0 = Ab + (size_t)(bm + r0) * lda + sl * 8;
    const u16* gA1 = gA0 + (size_t)128 * lda;
    const u16* gB0 = Bb + (size_t)(bn + r0) * ldb + sl * 8;
    const u16* gB1 = gB0 + (size_t)128 * ldb;

    const int fr  = lane & 15;
    const int kc  = lane >> 4;
    const int frb = fr * 64 + ((kc ^ ((fr >> 1) & 3)) << 4);

    floatx4 acc[2 * MIH][4];
#pragma unroll
    for (int i = 0; i < 2 * MIH; i++)
#pragma unroll
        for (int j = 0; j < 4; j++) acc[i][j] = (floatx4){0.f, 0.f, 0.f, 0.f};

    short8 aF[MIH][2], bLo[2][2], bHi[2][2];

    auto rdA = [&](short8 (&dst)[MIH][2], const char* bp, int miBase) {
#pragma unroll
        for (int m = 0; m < MIH; m++)
#pragma unroll
            for (int ks = 0; ks < 2; ks++)
                dst[m][ks] = *(const short8*)(bp + ks * ASLAB +
                    (wr * WM + (miBase + m) * 16) * 64 + frb);
    };
    auto rdB = [&](short8 (&dst)[2][2], const char* bp, int niBase) {
#pragma unroll
        for (int n = 0; n < 2; n++)
#pragma unroll
            for (int ks = 0; ks < 2; ks++)
                dst[n][ks] = *(const short8*)(bp + 2 * ASLAB + ks * BSLAB +
                    (wc * 64 + (niBase + n) * 16) * 64 + frb);
    };
    auto mf = [&](short8 (&av)[MIH][2], short8 (&bv)[2][2], int miB, int niB) {
        __builtin_amdgcn_s_setprio(1);
#pragma unroll
        for (int m = 0; m < MIH; m++)
#pragma unroll
            for (int n = 0; n < 2; n++)
#pragma unroll
                for (int ks = 0; ks < 2; ks++)
                    acc[miB + m][niB + n] = __builtin_amdgcn_mfma_f32_16x16x32_bf16(
                        av[m][ks], bv[n][ks], acc[miB + m][niB + n], 0, 0, 0);
        __builtin_amdgcn_s_setprio(0);
    };

#define STA(buf, ks, sc) do { \
    char* d = &lds[buf][(ks) * ASLAB] + wid * 1024; \
    gl16(gA0 + (sc) + (ks) * 32, (u16*)d); \
    if constexpr (WM == 128) gl16(gA1 + (sc) + (ks) * 32, (u16*)(d + 8192)); \
  } while (0)
#define STB(buf, ks, sc) do { \
    char* d = &lds[buf][2 * ASLAB + (ks) * BSLAB] + wid * 1024; \
    gl16(gB0 + (sc) + (ks) * 32, (u16*)d); \
    gl16(gB1 + (sc) + (ks) * 32, (u16*)(d + 8192)); \
  } while (0)

#define GROUP(q, S1, S2, S3, S4) { \
    const char* bp = &lds[q][0]; \
    rdA(aF, bp, 0); rdB(bLo, bp, 0); S1; PBAR(); LG0(); \
    mf(aF, bLo, 0, 0);   PBAR(); \
    rdB(bHi, bp, 2);                S2; PBAR(); LG0(); \
    mf(aF, bHi, 0, 2);   PBAR(); \
    rdA(aF, bp, MIH);               S3; PBAR(); LG0(); \
    mf(aF, bHi, MIH, 2); PBAR(); \
    S4; VM4(); PBAR(); \
    mf(aF, bLo, MIH, 0); PBAR(); \
}

    STA(0, 0, 0); STA(0, 1, 0); STB(0, 0, 0); STB(0, 1, 0);
    STB(1, 0, 64); STB(1, 1, 64);
    VM4(); PBAR();

    const int nk = K >> 6;
    for (int T = 0; T < nk; T += 2) {
        const int c1 = (T + 1) << 6;
        const int c2 = (T + 2 < nk ? T + 2 : nk - 1) << 6;
        const int c3 = (T + 3 < nk ? T + 3 : nk - 1) << 6;
        GROUP(0, STA(1, 0, c1), STA(1, 1, c1), STB(0, 0, c2), STB(0, 1, c2))
        GROUP(1, STA(0, 0, c2), STA(0, 1, c2), STB(1, 0, c3), STB(1, 1, c3))
    }
    asm volatile("s_waitcnt vmcnt(0)" ::: "memory");

#undef GROUP
#undef STB
#undef STA

    const int crow0 = bm + wr * WM + kc * 4;
    const int ccol0 = bn + wc * 64 + fr;
    const size_t coff = (size_t)sbz * sC;

    if (EPI == 1) {
        u16* C = (u16*)Cv;
#pragma unroll
        for (int mi = 0; mi < 2 * MIH; mi++)
#pragma unroll
            for (int ni = 0; ni < 4; ni++)
#pragma unroll
                for (int r = 0; r < 4; r++)
                    C[coff + (size_t)(crow0 + mi * 16 + r) * ldc + (ccol0 + ni * 16)] =
                        f32_bf16_rne(acc[mi][ni][r] * scale);
    } else {
        float* C = (float*)Cv;
#pragma unroll
        for (int mi = 0; mi < 2 * MIH; mi++)
#pragma unroll
            for (int ni = 0; ni < 4; ni++)
#pragma unroll
                for (int r = 0; r < 4; r++)
                    C[coff + (size_t)(crow0 + mi * 16 + r) * ldc + (ccol0 + ni * 16)] =
                        acc[mi][ni][r];
    }
}

// ------------------------------------------------- softmax + V transpose
// One launch, blockIdx split (R6-verified; R9: bf16 scores input):
//   blockIdx.x < TOKENS : row softmax, 2048 bf16 scores -> 2048 bf16 probs
//   blockIdx.x >= TOKENS: 64x64 V-transpose tile, qkv V-cols -> Vt
__global__ __launch_bounds__(256) void softmax_tr_kernel(
        const u16* __restrict__ S, u16* __restrict__ P,
        const u16* __restrict__ qkv, u16* __restrict__ Vt) {
    __shared__ float redm[4];
    __shared__ float reds[4];
    __shared__ u16 tile[64][66];
    const int t = threadIdx.x;

    if ((int)blockIdx.x < TOKENS) {
        const size_t base = (size_t)blockIdx.x * SEQ;
        const int lane = t & 63, wid = t >> 6;
        short8 raw = *(const short8*)(S + base + t * 8);   // 8 bf16 / thread
        float e[8];
#pragma unroll
        for (int j = 0; j < 8; j++) e[j] = bf16_f32((u16)raw[j]);

        float m = e[0];
#pragma unroll
        for (int j = 1; j < 8; j++) m = fmaxf(m, e[j]);
#pragma unroll
        for (int off = 32; off; off >>= 1) m = fmaxf(m, __shfl_xor(m, off, 64));
        if (lane == 0) redm[wid] = m;
        __syncthreads();
        m = fmaxf(fmaxf(redm[0], redm[1]), fmaxf(redm[2], redm[3]));

        float s = 0.f;
#pragma unroll
        for (int j = 0; j < 8; j++) { e[j] = __expf(e[j] - m); s += e[j]; }
#pragma unroll
        for (int off = 32; off; off >>= 1) s += __shfl_xor(s, off, 64);
        if (lane == 0) reds[wid] = s;
        __syncthreads();
        s = reds[0] + reds[1] + reds[2] + reds[3];
        const float r = 1.f / s;

        ushort8 o;
#pragma unroll
        for (int j = 0; j < 8; j++) o[j] = f32_bf16_rne(e[j] * r);
        *(ushort8*)(P + base + t * 8) = o;
    } else {
        // transposeV: Vt[b][h][s] <- qkv[b*SEQ+s][2*HIDDEN+h], 64x64 tiles
        const int bx = blockIdx.x - TOKENS;       // 0..2047
        const int b  = bx >> 9;                   // 32*16 tiles per batch
        const int s0 = (bx & 31) * 64;
        const int h0 = ((bx >> 5) & 15) * 64;
        const int c = t & 63, r4 = t >> 6;
#pragma unroll
        for (int i = 0; i < 16; i++) {
            int sl = i * 4 + r4;
            tile[sl][c] = qkv[(size_t)(b * SEQ + s0 + sl) * QKVD + 2 * HIDDEN + h0 + c];
        }
        __syncthreads();
#pragma unroll
        for (int i = 0; i < 16; i++) {
            int hl = i * 4 + r4;
            Vt[(size_t)(b * HIDDEN + h0 + hl) * SEQ + s0 + c] = tile[c][hl];
        }
    }
}

// ---------------------------------------------------------------- launch
extern "C" void kernel_launch(void* const* d_in, const int* in_sizes, int n_in,
                              void* d_out, int out_size, void* d_ws, size_t ws_size,
                              hipStream_t stream) {
    const float* x    = (const float*)d_in[0];   // [4,2048,1024]
    const float* W    = (const float*)d_in[1];   // [3072,1024]
    const float* bias = (const float*)d_in[2];   // [3072]
    float* out = (float*)d_out;                  // [4,2048,1024]

    // workspace layout (scores bf16 since R9)
    u16* Xb     = (u16*)d_ws;                               // 8192x1024 bf16
    u16* Wb     = Xb + (size_t)TOKENS * HIDDEN;             // 3072x1024 bf16
    u16* qkv    = Wb + (size_t)QKVD * HIDDEN;               // 8192x3072 bf16
    u16* scores = qkv + (size_t)TOKENS * QKVD;              // 4x2048x2048 bf16
    u16* P      = scores + (size_t)BATCH * SEQ * SEQ;       // 4x2048x2048 bf16
    u16* Vt     = P + (size_t)BATCH * SEQ * SEQ;            // 4x1024x2048 bf16

    // 1) fp32 -> bf16 casts (both tensors, one launch)
    {
        const int n4a = TOKENS * HIDDEN / 4;
        const int n4b = QKVD * HIDDEN / 4;
        const int n4t = n4a + n4b;
        cvt2_bf16_kernel<<<(n4t + 255) / 256, 256, 0, stream>>>(x, W, Xb, Wb, n4a, n4t);
    }

    // 2) QKV projection (R1 4-phase + XCD swizzle).  grid 12x64 = 768
    gemm_qkv<<<dim3(QKVD / 256, TOKENS / 128, 1), 512, 0, stream>>>(
        Xb, Wb, qkv, bias);

    // 3) scores = scale * Q @ K^T per batch (bf16 out)  grid 8x8x4 = 256
    gemm_bt<1, 128><<<dim3(SEQ / 256, SEQ / 256, BATCH), 512, 0, stream>>>(
        qkv, qkv + HIDDEN, scores, nullptr, HIDDEN, QKVD, QKVD, SEQ,
        (size_t)SEQ * QKVD, (size_t)SEQ * QKVD, (size_t)SEQ * SEQ, 0.03125f);

    // 4) row softmax (bf16 in) + V transpose in one launch (8192+2048 blocks)
    softmax_tr_kernel<<<TOKENS + 2048, 256, 0, stream>>>(scores, P, qkv, Vt);

    // 5) out = P @ Vt^T per batch (f32 out)  WM=64: grid 4x16x4 = 256
    gemm_bt<2, 64><<<dim3(HIDDEN / 256, SEQ / 128, BATCH), 512, 0, stream>>>(
        P, Vt, out, nullptr, SEQ, SEQ, SEQ, HIDDEN,
        (size_t)SEQ * SEQ, (size_t)HIDDEN * SEQ, (size_t)SEQ * HIDDEN, 1.f);
}

// Round 11
// 247.696 us; speedup vs baseline: 1.0107x; 1.0107x over previous
//
#include <hip/hip_runtime.h>
#include <stdint.h>

#define HIDDEN 1024
#define BATCH  4
#define SEQ    2048
#define TOKENS (BATCH * SEQ)      // 8192
#define QKVD   (3 * HIDDEN)       // 3072

typedef unsigned short u16;
typedef __attribute__((ext_vector_type(8))) short   short8;   // 8 bf16 = 4 VGPRs
typedef __attribute__((ext_vector_type(8))) unsigned short ushort8;
typedef __attribute__((ext_vector_type(4))) float   floatx4;

// deterministic round-to-nearest-even f32 -> bf16 (no NaN inputs here)
__device__ __forceinline__ u16 f32_bf16_rne(float f) {
    unsigned int u = __float_as_uint(f);
    u += 0x7FFFu + ((u >> 16) & 1u);
    return (u16)(u >> 16);
}
__device__ __forceinline__ float bf16_f32(u16 u) {
    return __uint_as_float(((unsigned int)u) << 16);
}

// async global->LDS, 16B per lane. LDS dest is wave-uniform base + lane*16.
__device__ __forceinline__ void gl16(const u16* g, u16* l) {
    __builtin_amdgcn_global_load_lds(
        (const __attribute__((address_space(1))) void*)g,
        (__attribute__((address_space(3))) void*)l, 16, 0, 0);
}

// T1: XCD-chunked bijective blockIdx swizzle.  Round-10 A/B result: -9% on
// QKV (grid 12x64: gx=12 % 8 != 0 -> default round-robin gives NO stable
// panel per XCD; chunking wins).  REGRESSED scores/PV (~+8us combined:
// their inputs are L3-resident and gx=8 divides 8, so default round-robin
// already pins one B-panel per XCD -- m160 "swizzle costs when L3-fit").
// => applied ONLY in gemm_qkv.
__device__ __forceinline__ void xcd_swizzle(int& bx, int& by, int& bz) {
    const int gx = gridDim.x, gy = gridDim.y;
    const int n  = gx * gy * gridDim.z;
    const int F  = (blockIdx.z * gy + blockIdx.y) * gx + blockIdx.x;
    const int nid = (F & 7) * (n >> 3) + (F >> 3);
    bx = nid % gx;
    by = (nid / gx) % gy;
    bz = nid / (gx * gy);
}

// ---- sync macros (verbatim from measured-best rounds)
// QKV 4-phase (R1): keep newest 3 staging loads in flight across barrier.
#define SYNC3() do { __builtin_amdgcn_sched_barrier(0); \
    asm volatile("s_waitcnt vmcnt(3)\n\ts_barrier" ::: "memory"); } while (0)
// R3 8-phase (scores/PV): raw barrier / lgkm drain / counted vmcnt(4)
#define PBAR() do { __builtin_amdgcn_sched_barrier(0); \
    asm volatile("s_barrier" ::: "memory"); } while (0)
#define LG0() asm volatile("s_waitcnt lgkmcnt(0)" ::: "memory")
#define VM4() do { __builtin_amdgcn_sched_barrier(0); \
    asm volatile("s_waitcnt vmcnt(4)" ::: "memory"); } while (0)

// ---------------------------------------------------------------- convert
__global__ __launch_bounds__(256) void cvt2_bf16_kernel(
        const float* __restrict__ sa, const float* __restrict__ sb,
        u16* __restrict__ da, u16* __restrict__ db, int n4a, int n4tot) {
    int i = blockIdx.x * 256 + threadIdx.x;
    if (i >= n4tot) return;
    float4 v;
    if (i < n4a) v = ((const float4*)sa)[i];
    else         v = ((const float4*)sb)[i - n4a];
    ushort4 o;
    o.x = f32_bf16_rne(v.x); o.y = f32_bf16_rne(v.y);
    o.z = f32_bf16_rne(v.z); o.w = f32_bf16_rne(v.w);
    if (i < n4a) ((ushort4*)da)[i] = o;
    else         ((ushort4*)db)[i - n4a] = o;
}

// ---------------------------------------------------------------- QKV GEMM
// qkv = Xb @ Wb^T + bias.  Round-1 4-phase kernel + XCD swizzle (R10: -9%,
// 70.4 -> 64.2us, session-best QKV).  BM=128, BN=256, BK=64, 512 threads =
// 8 waves (2M x 4N), per-wave 64x64.  Slab + XOR swizzle + vmcnt(3)
// pipeline verbatim (0 conflicts all session).
__global__ __launch_bounds__(512, 2) void gemm_qkv(
        const u16* __restrict__ A, const u16* __restrict__ B,
        u16* __restrict__ C, const float* __restrict__ bias) {
    __shared__ __align__(16) u16 lds[2][2][(128 + 256) * 32];   // 96 KB

    const int t    = threadIdx.x;
    const int lane = t & 63;
    const int wid  = t >> 6;
    const int wr   = wid >> 2;           // 0..1
    const int wc   = wid & 3;            // 0..3
    int sbx, sby, sbz;                   // grid (12, 64, 1): nwg=768, chunk=96
    xcd_swizzle(sbx, sby, sbz);
    const int bm   = sby * 128;
    const int bn   = sbx * 256;

    // staging source: thread t -> row t>>2, phys slot t&3,
    // global slot = (t&3) ^ ((row>>1)&3)
    const int rA  = t >> 2;
    const int sl  = (t & 3) ^ ((rA >> 1) & 3);
    const u16* gA  = A + (size_t)(bm + rA) * 1024 + sl * 8;
    const u16* gB0 = B + (size_t)(bn + rA) * 1024 + sl * 8;
    const u16* gB1 = gB0 + (size_t)128 * 1024;

    // fragment read geometry (verified 16x16x32 mappings)
    const int fr = lane & 15;
    const int kc = lane >> 4;
    const int fo = ((kc ^ ((fr >> 1) & 3)) << 4);
    const int aoffB = (wr * 64 + fr) * 64 + fo;
    const int boffB = (wc * 64 + fr) * 64 + fo;

    floatx4 acc[4][4];
#pragma unroll
    for (int i = 0; i < 4; i++)
#pragma unroll
        for (int j = 0; j < 4; j++) acc[i][j] = (floatx4){0.f, 0.f, 0.f, 0.f};

    short8 bfr0, bfr1, bfr2, bfr3, va0, va1;

#define LDB4(BASE) \
    bfr0 = *(const short8*)((BASE) + boffB);        \
    bfr1 = *(const short8*)((BASE) + boffB + 1024); \
    bfr2 = *(const short8*)((BASE) + boffB + 2048); \
    bfr3 = *(const short8*)((BASE) + boffB + 3072);

#define MFMA2(MI, A0, A1) \
    __builtin_amdgcn_s_setprio(1); \
    acc[MI][0]     = __builtin_amdgcn_mfma_f32_16x16x32_bf16(A0, bfr0, acc[MI][0], 0, 0, 0); \
    acc[MI][1]     = __builtin_amdgcn_mfma_f32_16x16x32_bf16(A0, bfr1, acc[MI][1], 0, 0, 0); \
    acc[MI][2]     = __builtin_amdgcn_mfma_f32_16x16x32_bf16(A0, bfr2, acc[MI][2], 0, 0, 0); \
    acc[MI][3]     = __builtin_amdgcn_mfma_f32_16x16x32_bf16(A0, bfr3, acc[MI][3], 0, 0, 0); \
    acc[(MI)+1][0] = __builtin_amdgcn_mfma_f32_16x16x32_bf16(A1, bfr0, acc[(MI)+1][0], 0, 0, 0); \
    acc[(MI)+1][1] = __builtin_amdgcn_mfma_f32_16x16x32_bf16(A1, bfr1, acc[(MI)+1][1], 0, 0, 0); \
    acc[(MI)+1][2] = __builtin_amdgcn_mfma_f32_16x16x32_bf16(A1, bfr2, acc[(MI)+1][2], 0, 0, 0); \
    acc[(MI)+1][3] = __builtin_amdgcn_mfma_f32_16x16x32_bf16(A1, bfr3, acc[(MI)+1][3], 0, 0, 0); \
    __builtin_amdgcn_s_setprio(0);

#define ITER(BUF, SBUF, SCOL) { \
    const char* As0_ = (const char*)&lds[BUF][0][0]; \
    const char* Bs0_ = As0_ + 8192; \
    const char* As1_ = (const char*)&lds[BUF][1][0]; \
    const char* Bs1_ = As1_ + 8192; \
    gl16(gA + (SCOL),       (u16*)((char*)&lds[SBUF][0][0]    + wid * 1024)); \
    LDB4(Bs0_); \
    va0 = *(const short8*)(As0_ + aoffB); \
    va1 = *(const short8*)(As0_ + aoffB + 1024); \
    MFMA2(0, va0, va1); \
    gl16(gB0 + (SCOL),      (u16*)((char*)&lds[SBUF][0][4096] + wid * 1024)); \
    gl16(gB1 + (SCOL),      (u16*)((char*)&lds[SBUF][0][8192] + wid * 1024)); \
    va0 = *(const short8*)(As0_ + aoffB + 2048); \
    va1 = *(const short8*)(As0_ + aoffB + 3072); \
    MFMA2(2, va0, va1); \
    SYNC3(); \
    gl16(gA + (SCOL) + 32,  (u16*)((char*)&lds[SBUF][1][0]    + wid * 1024)); \
    LDB4(Bs1_); \
    va0 = *(const short8*)(As1_ + aoffB); \
    va1 = *(const short8*)(As1_ + aoffB + 1024); \
    MFMA2(0, va0, va1); \
    gl16(gB0 + (SCOL) + 32, (u16*)((char*)&lds[SBUF][1][4096] + wid * 1024)); \
    gl16(gB1 + (SCOL) + 32, (u16*)((char*)&lds[SBUF][1][8192] + wid * 1024)); \
    va0 = *(const short8*)(As1_ + aoffB + 2048); \
    va1 = *(const short8*)(As1_ + aoffB + 3072); \
    MFMA2(2, va0, va1); \
    SYNC3(); }

    // prologue: tile 0 -> buf0 (ks0 set, ks1 set); vmcnt(3) drains the ks0
    // set, leaves the ks1 set in flight (= steady state).
    gl16(gA,       (u16*)((char*)&lds[0][0][0]    + wid * 1024));
    gl16(gB0,      (u16*)((char*)&lds[0][0][4096] + wid * 1024));
    gl16(gB1,      (u16*)((char*)&lds[0][0][8192] + wid * 1024));
    gl16(gA + 32,  (u16*)((char*)&lds[0][1][0]    + wid * 1024));
    gl16(gB0 + 32, (u16*)((char*)&lds[0][1][4096] + wid * 1024));
    gl16(gB1 + 32, (u16*)((char*)&lds[0][1][8192] + wid * 1024));
    SYNC3();

    const int nk = 1024 >> 6;            // 16 K-tiles
    for (int kt = 0; kt < nk; kt += 2) {
        const int c1 = (kt + 1) << 6;
        const int c2 = (kt + 2 < nk ? (kt + 2) : (nk - 1)) << 6;
        ITER(0, 1, c1)
        ITER(1, 0, c2)
    }
    asm volatile("s_waitcnt vmcnt(0)" ::: "memory");

#undef ITER
#undef MFMA2
#undef LDB4

    // epilogue: C/D 16x16 mapping col=lane&15, row=(lane>>4)*4+reg
    const int crow0 = bm + wr * 64 + kc * 4;
    const int ccol0 = bn + wc * 64 + fr;
    float bv[4];
#pragma unroll
    for (int ni = 0; ni < 4; ni++) bv[ni] = bias[ccol0 + ni * 16];
#pragma unroll
    for (int mi = 0; mi < 4; mi++)
#pragma unroll
        for (int ni = 0; ni < 4; ni++)
#pragma unroll
            for (int r = 0; r < 4; r++)
                C[(size_t)(crow0 + mi * 16 + r) * QKVD + (ccol0 + ni * 16)] =
                    f32_bf16_rne(acc[mi][ni][r] + bv[ni]);
}

// ---------------------------------------------------------------- GEMM (NT)
// Round-3 8-phase template (measured best for scores+PV), NO swizzle (R10
// A/B: swizzle regressed these L3-resident-input GEMMs by ~8us combined).
// C[M,N] = A[M,K]*B[N,K]^T.  BM=2*WM, BN=256, BK=64, 512 threads, 8 waves.
// EPI: 1 = bf16 store * scale (R9: halves scores write + softmax read);
//      2 = f32 store.
template <int EPI, int WM>
__global__ __launch_bounds__(512, 2) void gemm_bt(
        const u16* __restrict__ A, const u16* __restrict__ B,
        void* __restrict__ Cv, const float* __restrict__ bias,
        int K, int lda, int ldb, int ldc,
        size_t sA, size_t sB, size_t sC, float scale) {
    constexpr int BM    = 2 * WM;
    constexpr int MIH   = WM / 32;
    constexpr int ASLAB = BM * 64;
    constexpr int BSLAB = 256 * 64;
    constexpr int BUFB  = 2 * ASLAB + 2 * BSLAB;
    __shared__ __align__(16) char lds[2][BUFB];

    const int t    = threadIdx.x;
    const int lane = t & 63;
    const int wid  = t >> 6;
    const int wr   = wid >> 2;
    const int wc   = wid & 3;
    const int bm   = blockIdx.y * BM;
    const int bn   = blockIdx.x * 256;

    const u16* Ab = A + (size_t)blockIdx.z * sA;
    const u16* Bb = B + (size_t)blockIdx.z * sB;

    const int r0 = t >> 2;
    const int sl = (t & 3) ^ ((r0 >> 1) & 3);
    const u16* gA0 = Ab + (size_t)(bm + r0) * lda + sl * 8;
    const u16* gA1 = gA0 + (size_t)128 * lda;
    const u16* gB0 = Bb + (size_t)(bn + r0) * ldb + sl * 8;
    const u16* gB1 = gB0 + (size_t)128 * ldb;

    const int fr  = lane & 15;
    const int kc  = lane >> 4;
    const int frb = fr * 64 + ((kc ^ ((fr >> 1) & 3)) << 4);

    floatx4 acc[2 * MIH][4];
#pragma unroll
    for (int i = 0; i < 2 * MIH; i++)
#pragma unroll
        for (int j = 0; j < 4; j++) acc[i][j] = (floatx4){0.f, 0.f, 0.f, 0.f};

    short8 aF[MIH][2], bLo[2][2], bHi[2][2];

    auto rdA = [&](short8 (&dst)[MIH][2], const char* bp, int miBase) {
#pragma unroll
        for (int m = 0; m < MIH; m++)
#pragma unroll
            for (int ks = 0; ks < 2; ks++)
                dst[m][ks] = *(const short8*)(bp + ks * ASLAB +
                    (wr * WM + (miBase + m) * 16) * 64 + frb);
    };
    auto rdB = [&](short8 (&dst)[2][2], const char* bp, int niBase) {
#pragma unroll
        for (int n = 0; n < 2; n++)
#pragma unroll
            for (int ks = 0; ks < 2; ks++)
                dst[n][ks] = *(const short8*)(bp + 2 * ASLAB + ks * BSLAB +
                    (wc * 64 + (niBase + n) * 16) * 64 + frb);
    };
    auto mf = [&](short8 (&av)[MIH][2], short8 (&bv)[2][2], int miB, int niB) {
        __builtin_amdgcn_s_setprio(1);
#pragma unroll
        for (int m = 0; m < MIH; m++)
#pragma unroll
            for (int n = 0; n < 2; n++)
#pragma unroll
                for (int ks = 0; ks < 2; ks++)
                    acc[miB + m][niB + n] = __builtin_amdgcn_mfma_f32_16x16x32_bf16(
                        av[m][ks], bv[n][ks], acc[miB + m][niB + n], 0, 0, 0);
        __builtin_amdgcn_s_setprio(0);
    };

#define STA(buf, ks, sc) do { \
    char* d = &lds[buf][(ks) * ASLAB] + wid * 1024; \
    gl16(gA0 + (sc) + (ks) * 32, (u16*)d); \
    if constexpr (WM == 128) gl16(gA1 + (sc) + (ks) * 32, (u16*)(d + 8192)); \
  } while (0)
#define STB(buf, ks, sc) do { \
    char* d = &lds[buf][2 * ASLAB + (ks) * BSLAB] + wid * 1024; \
    gl16(gB0 + (sc) + (ks) * 32, (u16*)d); \
    gl16(gB1 + (sc) + (ks) * 32, (u16*)(d + 8192)); \
  } while (0)

#define GROUP(q, S1, S2, S3, S4) { \
    const char* bp = &lds[q][0]; \
    rdA(aF, bp, 0); rdB(bLo, bp, 0); S1; PBAR(); LG0(); \
    mf(aF, bLo, 0, 0);   PBAR(); \
    rdB(bHi, bp, 2);                S2; PBAR(); LG0(); \
    mf(aF, bHi, 0, 2);   PBAR(); \
    rdA(aF, bp, MIH);               S3; PBAR(); LG0(); \
    mf(aF, bHi, MIH, 2); PBAR(); \
    S4; VM4(); PBAR(); \
    mf(aF, bLo, MIH, 0); PBAR(); \
}

    STA(0, 0, 0); STA(0, 1, 0); STB(0, 0, 0); STB(0, 1, 0);
    STB(1, 0, 64); STB(1, 1, 64);
    VM4(); PBAR();

    const int nk = K >> 6;
    for (int T = 0; T < nk; T += 2) {
        const int c1 = (T + 1) << 6;
        const int c2 = (T + 2 < nk ? T + 2 : nk - 1) << 6;
        const int c3 = (T + 3 < nk ? T + 3 : nk - 1) << 6;
        GROUP(0, STA(1, 0, c1), STA(1, 1, c1), STB(0, 0, c2), STB(0, 1, c2))
        GROUP(1, STA(0, 0, c2), STA(0, 1, c2), STB(1, 0, c3), STB(1, 1, c3))
    }
    asm volatile("s_waitcnt vmcnt(0)" ::: "memory");

#undef GROUP
#undef STB
#undef STA

    const int crow0 = bm + wr * WM + kc * 4;
    const int ccol0 = bn + wc * 64 + fr;
    const size_t coff = (size_t)blockIdx.z * sC;

    if (EPI == 1) {
        u16* C = (u16*)Cv;
#pragma unroll
        for (int mi = 0; mi < 2 * MIH; mi++)
#pragma unroll
            for (int ni = 0; ni < 4; ni++)
#pragma unroll
                for (int r = 0; r < 4; r++)
                    C[coff + (size_t)(crow0 + mi * 16 + r) * ldc + (ccol0 + ni * 16)] =
                        f32_bf16_rne(acc[mi][ni][r] * scale);
    } else {
        float* C = (float*)Cv;
#pragma unroll
        for (int mi = 0; mi < 2 * MIH; mi++)
#pragma unroll
            for (int ni = 0; ni < 4; ni++)
#pragma unroll
                for (int r = 0; r < 4; r++)
                    C[coff + (size_t)(crow0 + mi * 16 + r) * ldc + (ccol0 + ni * 16)] =
                        acc[mi][ni][r];
    }
}

// ------------------------------------------------- softmax + V transpose
// One launch, blockIdx split (R6-verified; R9: bf16 scores input):
//   blockIdx.x < TOKENS : row softmax, 2048 bf16 scores -> 2048 bf16 probs
//   blockIdx.x >= TOKENS: 64x64 V-transpose tile, qkv V-cols -> Vt
__global__ __launch_bounds__(256) void softmax_tr_kernel(
        const u16* __restrict__ S, u16* __restrict__ P,
        const u16* __restrict__ qkv, u16* __restrict__ Vt) {
    __shared__ float redm[4];
    __shared__ float reds[4];
    __shared__ u16 tile[64][66];
    const int t = threadIdx.x;

    if ((int)blockIdx.x < TOKENS) {
        const size_t base = (size_t)blockIdx.x * SEQ;
        const int lane = t & 63, wid = t >> 6;
        short8 raw = *(const short8*)(S + base + t * 8);   // 8 bf16 / thread
        float e[8];
#pragma unroll
        for (int j = 0; j < 8; j++) e[j] = bf16_f32((u16)raw[j]);

        float m = e[0];
#pragma unroll
        for (int j = 1; j < 8; j++) m = fmaxf(m, e[j]);
#pragma unroll
        for (int off = 32; off; off >>= 1) m = fmaxf(m, __shfl_xor(m, off, 64));
        if (lane == 0) redm[wid] = m;
        __syncthreads();
        m = fmaxf(fmaxf(redm[0], redm[1]), fmaxf(redm[2], redm[3]));

        float s = 0.f;
#pragma unroll
        for (int j = 0; j < 8; j++) { e[j] = __expf(e[j] - m); s += e[j]; }
#pragma unroll
        for (int off = 32; off; off >>= 1) s += __shfl_xor(s, off, 64);
        if (lane == 0) reds[wid] = s;
        __syncthreads();
        s = reds[0] + reds[1] + reds[2] + reds[3];
        const float r = 1.f / s;

        ushort8 o;
#pragma unroll
        for (int j = 0; j < 8; j++) o[j] = f32_bf16_rne(e[j] * r);
        *(ushort8*)(P + base + t * 8) = o;
    } else {
        // transposeV: Vt[b][h][s] <- qkv[b*SEQ+s][2*HIDDEN+h], 64x64 tiles
        const int bx = blockIdx.x - TOKENS;       // 0..2047
        const int b  = bx >> 9;                   // 32*16 tiles per batch
        const int s0 = (bx & 31) * 64;
        const int h0 = ((bx >> 5) & 15) * 64;
        const int c = t & 63, r4 = t >> 6;
#pragma unroll
        for (int i = 0; i < 16; i++) {
            int sl = i * 4 + r4;
            tile[sl][c] = qkv[(size_t)(b * SEQ + s0 + sl) * QKVD + 2 * HIDDEN + h0 + c];
        }
        __syncthreads();
#pragma unroll
        for (int i = 0; i < 16; i++) {
            int hl = i * 4 + r4;
            Vt[(size_t)(b * HIDDEN + h0 + hl) * SEQ + s0 + c] = tile[c][hl];
        }
    }
}

// ---------------------------------------------------------------- launch
extern "C" void kernel_launch(void* const* d_in, const int* in_sizes, int n_in,
                              void* d_out, int out_size, void* d_ws, size_t ws_size,
                              hipStream_t stream) {
    const float* x    = (const float*)d_in[0];   // [4,2048,1024]
    const float* W    = (const float*)d_in[1];   // [3072,1024]
    const float* bias = (const float*)d_in[2];   // [3072]
    float* out = (float*)d_out;                  // [4,2048,1024]

    // workspace layout (scores bf16 since R9)
    u16* Xb     = (u16*)d_ws;                               // 8192x1024 bf16
    u16* Wb     = Xb + (size_t)TOKENS * HIDDEN;             // 3072x1024 bf16
    u16* qkv    = Wb + (size_t)QKVD * HIDDEN;               // 8192x3072 bf16
    u16* scores = qkv + (size_t)TOKENS * QKVD;              // 4x2048x2048 bf16
    u16* P      = scores + (size_t)BATCH * SEQ * SEQ;       // 4x2048x2048 bf16
    u16* Vt     = P + (size_t)BATCH * SEQ * SEQ;            // 4x1024x2048 bf16

    // 1) fp32 -> bf16 casts (both tensors, one launch)
    {
        const int n4a = TOKENS * HIDDEN / 4;
        const int n4b = QKVD * HIDDEN / 4;
        const int n4t = n4a + n4b;
        cvt2_bf16_kernel<<<(n4t + 255) / 256, 256, 0, stream>>>(x, W, Xb, Wb, n4a, n4t);
    }

    // 2) QKV projection (R1 4-phase + XCD swizzle).  grid 12x64 = 768
    gemm_qkv<<<dim3(QKVD / 256, TOKENS / 128, 1), 512, 0, stream>>>(
        Xb, Wb, qkv, bias);

    // 3) scores = scale * Q @ K^T per batch (bf16 out, no swizzle)  8x8x4
    gemm_bt<1, 128><<<dim3(SEQ / 256, SEQ / 256, BATCH), 512, 0, stream>>>(
        qkv, qkv + HIDDEN, scores, nullptr, HIDDEN, QKVD, QKVD, SEQ,
        (size_t)SEQ * QKVD, (size_t)SEQ * QKVD, (size_t)SEQ * SEQ, 0.03125f);

    // 4) row softmax (bf16 in) + V transpose in one launch (8192+2048 blocks)
    softmax_tr_kernel<<<TOKENS + 2048, 256, 0, stream>>>(scores, P, qkv, Vt);

    // 5) out = P @ Vt^T per batch (f32 out, no swizzle)  WM=64: 4x16x4
    gemm_bt<2, 64><<<dim3(HIDDEN / 256, SEQ / 128, BATCH), 512, 0, stream>>>(
        P, Vt, out, nullptr, SEQ, SEQ, SEQ, HIDDEN,
        (size_t)SEQ * SEQ, (size_t)HIDDEN * SEQ, (size_t)SEQ * HIDDEN, 1.f);
}